// Round 1
// baseline (349.715 us; speedup 1.0000x reference)
//
#include <hip/hip_runtime.h>

// VanillaNerfVoxelModel: gather from 256^3x4 f32 voxel grid + sigmoid/relu.
// pos: (N,3) f32 in [-0.6,0.6]; in-bounds iff |v|<0.5 on all axes.
// idx = trunc(v*256 + 128)  (positive range -> trunc == floor)
// out = [colors (N,3) f32 ; density (N,) f32] concatenated.
//
// v2: 4 points/thread.
//   - pos read as 3x float4 (48B contiguous per thread, fully coalesced)
//   - index packed as (ix<<16)|(iy<<8)|iz (no 64-bit muls)
//   - 4 gathers issued unconditionally back-to-back (OOB lanes read grid[0],
//     a single broadcast line) -> 4x memory-level parallelism, no divergence
//   - colors written as 3x float4, density as 1x float4

#define GRID_RES 256

__device__ __forceinline__ float fast_sigmoid(float v) {
    return 1.0f / (1.0f + __expf(-v));
}

__global__ __launch_bounds__(256) void nerf_voxel_kernel_x4(
    const float4* __restrict__ pos4,     // nv*3 float4 (12 floats = 4 points)
    const float4* __restrict__ grid,     // 256^3 float4
    float4* __restrict__ colors4,        // nv*3 float4
    float4* __restrict__ density4,       // nv float4
    int nv)
{
    int t = blockIdx.x * blockDim.x + threadIdx.x;
    if (t >= nv) return;

    float4 p0 = pos4[3 * t + 0];
    float4 p1 = pos4[3 * t + 1];
    float4 p2 = pos4[3 * t + 2];

    // Deinterleave [x0 y0 z0 x1 | y1 z1 x2 y2 | z2 x3 y3 z3]
    float xs[4] = {p0.x, p0.w, p1.z, p2.y};
    float ys[4] = {p0.y, p1.x, p1.w, p2.z};
    float zs[4] = {p0.z, p1.y, p2.x, p2.w};

    bool cond[4];
    unsigned idx[4];
#pragma unroll
    for (int k = 0; k < 4; ++k) {
        bool c = (fabsf(xs[k]) < 0.5f) & (fabsf(ys[k]) < 0.5f) & (fabsf(zs[k]) < 0.5f);
        // Match numpy's separate mul+add rounding (no FMA contraction).
        int ix = c ? (int)(__fadd_rn(__fmul_rn(xs[k], 256.0f), 128.0f)) : 0;
        int iy = c ? (int)(__fadd_rn(__fmul_rn(ys[k], 256.0f), 128.0f)) : 0;
        int iz = c ? (int)(__fadd_rn(__fmul_rn(zs[k], 256.0f), 128.0f)) : 0;
        cond[k] = c;
        idx[k] = ((unsigned)ix << 16) | ((unsigned)iy << 8) | (unsigned)iz;
    }

    // Four independent gathers in flight (OOB -> grid[0], broadcast line).
    float4 g0 = grid[idx[0]];
    float4 g1 = grid[idx[1]];
    float4 g2 = grid[idx[2]];
    float4 g3 = grid[idx[3]];

    const float4 zero = make_float4(0.0f, 0.0f, 0.0f, 0.0f);
    if (!cond[0]) g0 = zero;   // cndmask, not a branch
    if (!cond[1]) g1 = zero;
    if (!cond[2]) g2 = zero;
    if (!cond[3]) g3 = zero;

    float4 c0 = make_float4(fast_sigmoid(g0.x), fast_sigmoid(g0.y),
                            fast_sigmoid(g0.z), fast_sigmoid(g1.x));
    float4 c1 = make_float4(fast_sigmoid(g1.y), fast_sigmoid(g1.z),
                            fast_sigmoid(g2.x), fast_sigmoid(g2.y));
    float4 c2 = make_float4(fast_sigmoid(g2.z), fast_sigmoid(g3.x),
                            fast_sigmoid(g3.y), fast_sigmoid(g3.z));
    float4 dd = make_float4(fmaxf(g0.w, 0.0f), fmaxf(g1.w, 0.0f),
                            fmaxf(g2.w, 0.0f), fmaxf(g3.w, 0.0f));

    colors4[3 * t + 0] = c0;
    colors4[3 * t + 1] = c1;
    colors4[3 * t + 2] = c2;
    density4[t] = dd;
}

// ---- Scalar fallback (n % 4 != 0; keeps density base alignment safe) -----
__global__ __launch_bounds__(256) void nerf_voxel_kernel_scalar(
    const float* __restrict__ pos,
    const float4* __restrict__ grid,
    float* __restrict__ colors,
    float* __restrict__ density,
    int n)
{
    int i = blockIdx.x * blockDim.x + threadIdx.x;
    if (i >= n) return;

    float x = pos[3 * i + 0];
    float y = pos[3 * i + 1];
    float z = pos[3 * i + 2];

    bool cond = (fabsf(x) < 0.5f) & (fabsf(y) < 0.5f) & (fabsf(z) < 0.5f);

    int ix = cond ? (int)(__fadd_rn(__fmul_rn(x, 256.0f), 128.0f)) : 0;
    int iy = cond ? (int)(__fadd_rn(__fmul_rn(y, 256.0f), 128.0f)) : 0;
    int iz = cond ? (int)(__fadd_rn(__fmul_rn(z, 256.0f), 128.0f)) : 0;
    unsigned idx = ((unsigned)ix << 16) | ((unsigned)iy << 8) | (unsigned)iz;

    float4 cad = grid[idx];
    if (!cond) cad = make_float4(0.0f, 0.0f, 0.0f, 0.0f);

    colors[3 * i + 0] = fast_sigmoid(cad.x);
    colors[3 * i + 1] = fast_sigmoid(cad.y);
    colors[3 * i + 2] = fast_sigmoid(cad.z);
    density[i] = fmaxf(cad.w, 0.0f);
}

extern "C" void kernel_launch(void* const* d_in, const int* in_sizes, int n_in,
                              void* d_out, int out_size, void* d_ws, size_t ws_size,
                              hipStream_t stream) {
    const float*  pos  = (const float*)d_in[0];
    const float4* grid = (const float4*)d_in[1];

    int n = in_sizes[0] / 3;                  // 2,000,000 points
    float* colors  = (float*)d_out;           // first 3*n floats
    float* density = colors + (size_t)3 * n;  // next n floats

    const int block = 256;
    if ((n & 3) == 0) {
        int nv = n >> 2;                      // 500,000 packets of 4 points
        int gridsz = (nv + block - 1) / block;
        hipLaunchKernelGGL(nerf_voxel_kernel_x4, dim3(gridsz), dim3(block), 0, stream,
                           (const float4*)pos, grid,
                           (float4*)colors, (float4*)density, nv);
    } else {
        int gridsz = (n + block - 1) / block;
        hipLaunchKernelGGL(nerf_voxel_kernel_scalar, dim3(gridsz), dim3(block), 0, stream,
                           pos, grid, colors, density, n);
    }
}